// Round 8
// baseline (385.159 us; speedup 1.0000x reference)
//
#include <hip/hip_runtime.h>

#define NEG_SLOPE 0.2f

static const int B = 4, N = 50000, R = 100000, E = 1600000;
static const int X2_CAP = 4096;     // x2 edge records (expected ~64)
static const int R2_CAP = 4096;     // r2 rows (expected ~64)
static const int N1_CAP = 4096;     // n1 nodes (expected ~1k)
static const int RS_CAP = 49152;    // row slots, r2 + r1 (expected ~28k)
static const int WDEG  = 64;        // w-CSR slab per slot (mean deg 16)
static const int WIDEG = 96;        // wi-CSR slab per n1 slot (mean deg 32)
static const int RBW = 3200;        // bit-words for R rows
static const int NBW = 1600;        // bit-words for N nodes
static const int ZWORDS = RS_CAP + N1_CAP + RBW + NBW + 8;
// tails: [0]=x2tail [1]=unused [2]=n1tail [3]=slotTail [4]=r2c snapshot [5]=doneCtr

// ---- scanA: wi edges with row>=N-2 -> x2list + r2 rows get slots [0,r2c) ----
__global__ void scanA(const int4* __restrict__ wi_rows4, const int4* __restrict__ wi_cols4,
                      const float4* __restrict__ wi_val4,
                      unsigned* __restrict__ bitsRS, int* __restrict__ rslot,
                      int2* __restrict__ x2list, int* __restrict__ tails, int e4) {
    int i = blockIdx.x * blockDim.x + threadIdx.x;
    if (i >= e4) return;
    int4 r = wi_rows4[i];
    int rr[4] = {r.x, r.y, r.z, r.w};
    bool any = false;
#pragma unroll
    for (int j = 0; j < 4; ++j) any = any || (rr[j] >= N - 2);
    if (!any) return;
    int4 c = wi_cols4[i];
    float4 v = wi_val4[i];
    int cc[4] = {c.x, c.y, c.z, c.w};
    float vv[4] = {v.x, v.y, v.z, v.w};
#pragma unroll
    for (int j = 0; j < 4; ++j) {
        if (rr[j] >= N - 2) {
            int col = cc[j];
            unsigned m = 1u << (col & 31);
            unsigned old = atomicOr(&bitsRS[col >> 5], m);
            if (!(old & m)) {
                int s = atomicAdd(&tails[3], 1);   // ~64 winners: negligible
                if (s < RS_CAP) rslot[col] = s;
            }
            int q = atomicAdd(&tails[0], 1);
            if (q < X2_CAP)
                x2list[q] = make_int2(col * 2 + (rr[j] - (N - 2)),
                                      __float_as_int(vv[j]));
        }
    }
}

// ---- scanB: w edges with row in r2 (bitsRS) -> n1 set, slot via block-agg ----
__global__ void scanB(const int4* __restrict__ w_rows4, const int4* __restrict__ w_cols4,
                      const unsigned* __restrict__ bitsRS, unsigned* __restrict__ bitsN1,
                      int* __restrict__ n1slot, int* __restrict__ tails, int e4) {
    __shared__ int lcount, gbase;
    __shared__ int buf[1024];
    if (threadIdx.x == 0) {
        lcount = 0;
        if (blockIdx.x == 0) tails[4] = tails[3];   // snapshot r2c
    }
    __syncthreads();
    int lane = threadIdx.x & 63;
    int i = blockIdx.x * blockDim.x + threadIdx.x;
    int4 r = make_int4(-1, -1, -1, -1);
    if (i < e4) r = w_rows4[i];
    int rr[4] = {r.x, r.y, r.z, r.w};
    unsigned fb[4];
#pragma unroll
    for (int j = 0; j < 4; ++j)
        fb[j] = (rr[j] >= 0) ? ((bitsRS[rr[j] >> 5] >> (rr[j] & 31)) & 1u) : 0u;
    bool anyf = (fb[0] | fb[1] | fb[2] | fb[3]) != 0u;
    int4 c = make_int4(0, 0, 0, 0);
    if (anyf) c = w_cols4[i];
    int cc[4] = {c.x, c.y, c.z, c.w};
#pragma unroll
    for (int j = 0; j < 4; ++j) {
        bool isnew = false;
        int n = 0;
        if (fb[j]) {
            n = cc[j];
            unsigned m = 1u << (n & 31);
            unsigned old = atomicOr(&bitsN1[n >> 5], m);
            isnew = (old & m) == 0u;
        }
        unsigned long long mb = __ballot(isnew);
        if (mb) {
            int leader = __ffsll(mb) - 1;
            int b0 = 0;
            if (lane == leader) b0 = atomicAdd(&lcount, __popcll(mb));
            b0 = __shfl(b0, leader);
            if (isnew) {
                int p = b0 + __popcll(mb & ((1ull << lane) - 1));
                if (p < 1024) buf[p] = n;
            }
        }
    }
    __syncthreads();
    int lc = lcount; if (lc > 1024) lc = 1024;
    if (threadIdx.x == 0 && lc > 0) gbase = atomicAdd(&tails[2], lc);
    __syncthreads();
    for (int t = threadIdx.x; t < lc; t += blockDim.x) {
        int slot = gbase + t;
        if (slot < N1_CAP) n1slot[buf[t]] = slot;
    }
}

// ---- scanC: wi edges with node-row in n1 -> wi-place + r1 slots (block-agg) ----
__global__ void scanC(const int4* __restrict__ wi_rows4, const int4* __restrict__ wi_cols4,
                      const float4* __restrict__ wi_val4, const float* __restrict__ diag1,
                      const unsigned* __restrict__ bitsN1, const int* __restrict__ n1slot,
                      unsigned* __restrict__ bitsRS, int* __restrict__ rslot,
                      int* __restrict__ wi_cntC, int2* __restrict__ wi_pairs,
                      int* __restrict__ tails, int e4) {
    __shared__ int lcount, gbase;
    __shared__ int buf[1024];
    if (threadIdx.x == 0) lcount = 0;
    __syncthreads();
    int lane = threadIdx.x & 63;
    int i = blockIdx.x * blockDim.x + threadIdx.x;
    int4 r = make_int4(-1, -1, -1, -1);
    if (i < e4) r = wi_rows4[i];
    int rr[4] = {r.x, r.y, r.z, r.w};
    unsigned fb[4];
#pragma unroll
    for (int j = 0; j < 4; ++j)
        fb[j] = (rr[j] >= 0) ? ((bitsN1[rr[j] >> 5] >> (rr[j] & 31)) & 1u) : 0u;
    bool anyf = (fb[0] | fb[1] | fb[2] | fb[3]) != 0u;
    int4 c = make_int4(0, 0, 0, 0);
    float4 v = make_float4(0.f, 0.f, 0.f, 0.f);
    if (anyf) { c = wi_cols4[i]; v = wi_val4[i]; }
    int cc[4] = {c.x, c.y, c.z, c.w};
    float vv[4] = {v.x, v.y, v.z, v.w};
#pragma unroll
    for (int j = 0; j < 4; ++j) {
        bool isnew = false;
        int col = 0;
        if (fb[j]) {
            col = cc[j];
            float cf = vv[j] * diag1[col];
            int slot = n1slot[rr[j]];
            if (slot >= 0 && slot < N1_CAP) {
                int pos = atomicAdd(&wi_cntC[slot], 1);
                if (pos < WIDEG)
                    wi_pairs[(size_t)slot * WIDEG + pos] =
                        make_int2(col, __float_as_int(cf));
            }
            unsigned m = 1u << (col & 31);
            unsigned old = atomicOr(&bitsRS[col >> 5], m);
            isnew = (old & m) == 0u;
        }
        unsigned long long mb = __ballot(isnew);
        if (mb) {
            int leader = __ffsll(mb) - 1;
            int b0 = 0;
            if (lane == leader) b0 = atomicAdd(&lcount, __popcll(mb));
            b0 = __shfl(b0, leader);
            if (isnew) {
                int p = b0 + __popcll(mb & ((1ull << lane) - 1));
                if (p < 1024) buf[p] = col;
            }
        }
    }
    __syncthreads();
    int lc = lcount; if (lc > 1024) lc = 1024;
    if (threadIdx.x == 0 && lc > 0) gbase = atomicAdd(&tails[3], lc);
    __syncthreads();
    for (int t = threadIdx.x; t < lc; t += blockDim.x) {
        int s = gbase + t;
        if (s < RS_CAP) rslot[buf[t]] = s;
    }
}

// ---- scanD: w edges with slotted row (r1|r2) -> compact w-slab place ----
__global__ void scanD(const int4* __restrict__ w_rows4, const int4* __restrict__ w_cols4,
                      const float4* __restrict__ w_val4,
                      const unsigned* __restrict__ bitsRS, const int* __restrict__ rslot,
                      int* __restrict__ w_cntC, int2* __restrict__ w_pairs, int e4) {
    int i = blockIdx.x * blockDim.x + threadIdx.x;
    if (i >= e4) return;
    int4 r = w_rows4[i];
    int rr[4] = {r.x, r.y, r.z, r.w};
    unsigned fb[4];
#pragma unroll
    for (int j = 0; j < 4; ++j) fb[j] = (bitsRS[rr[j] >> 5] >> (rr[j] & 31)) & 1u;
    if (!(fb[0] | fb[1] | fb[2] | fb[3])) return;
    int4 c = w_cols4[i];
    float4 v = w_val4[i];
    int cc[4] = {c.x, c.y, c.z, c.w};
    float vv[4] = {v.x, v.y, v.z, v.w};
    int s[4];
#pragma unroll
    for (int j = 0; j < 4; ++j) s[j] = fb[j] ? rslot[rr[j]] : RS_CAP;
#pragma unroll
    for (int j = 0; j < 4; ++j) {
        if (fb[j] && s[j] >= 0 && s[j] < RS_CAP) {
            int pos = atomicAdd(&w_cntC[s[j]], 1);
            if (pos < WDEG)
                w_pairs[(size_t)s[j] * WDEG + pos] =
                    make_int2(cc[j], __float_as_int(vv[j]));
        }
    }
}

// ---- gather_t1: per slot, t1C[s] = sum_w v * x[col]  (32 threads/slot) ----
__global__ void gather_t1(const float* __restrict__ x, float* __restrict__ t1C,
                          const int* __restrict__ w_cntC, const int2* __restrict__ w_pairs,
                          const int* __restrict__ tails) {
    int tot = tails[3]; if (tot > RS_CAP) tot = RS_CAP;
    int total = tot * 32;
    int gstride = gridDim.x * blockDim.x;
    for (int idx = blockIdx.x * blockDim.x + threadIdx.x; idx < total; idx += gstride) {
        int s = idx >> 5;
        int rem = idx & 31;
        int c4 = rem & 7;
        int b = rem >> 3;
        int L = w_cntC[s]; if (L > WDEG) L = WDEG;
        const int2* pr = w_pairs + (size_t)s * WDEG;
        const float4* sb = (const float4*)x + (size_t)b * N * 8 + c4;
        float4 acc = make_float4(0.f, 0.f, 0.f, 0.f);
        int i = 0;
        int L4 = L & ~3;
        for (; i < L4; i += 4) {
            int2 p0 = pr[i + 0];
            int2 p1 = pr[i + 1];
            int2 p2 = pr[i + 2];
            int2 p3 = pr[i + 3];
            float4 s0 = sb[(size_t)p0.x * 8];
            float4 s1 = sb[(size_t)p1.x * 8];
            float4 s2 = sb[(size_t)p2.x * 8];
            float4 s3 = sb[(size_t)p3.x * 8];
            float v0 = __int_as_float(p0.y), v1 = __int_as_float(p1.y);
            float v2 = __int_as_float(p2.y), v3 = __int_as_float(p3.y);
            acc.x += v0 * s0.x + v1 * s1.x + v2 * s2.x + v3 * s3.x;
            acc.y += v0 * s0.y + v1 * s1.y + v2 * s2.y + v3 * s3.y;
            acc.z += v0 * s0.z + v1 * s1.z + v2 * s2.z + v3 * s3.z;
            acc.w += v0 * s0.w + v1 * s1.w + v2 * s2.w + v3 * s3.w;
        }
        for (; i < L; ++i) {
            int2 p = pr[i];
            float4 sv = sb[(size_t)p.x * 8];
            float v = __int_as_float(p.y);
            acc.x += v * sv.x; acc.y += v * sv.y; acc.z += v * sv.z; acc.w += v * sv.w;
        }
        ((float4*)t1C)[(size_t)s * 32 + b * 8 + c4] = acc;
    }
}

// ---- x1mlp: per n1 slot, u = wi-agg(t1C); h2C = lrelu(u@W1)@W2.
//      LAST block to finish also runs: t2 gather + x2 accumulation + heads. ----
__global__ void __launch_bounds__(256) x1mlp(
        const float* __restrict__ W1, const float* __restrict__ W2,
        int* __restrict__ tails,
        const int* __restrict__ wi_cntC, const int2* __restrict__ wi_pairs,
        const int* __restrict__ rslot, const float* __restrict__ t1C,
        float* __restrict__ h2C,
        const int* __restrict__ w_cntC, const int2* __restrict__ w_pairs,
        const int* __restrict__ n1slot, float* __restrict__ t2C,
        const int2* __restrict__ x2list, const float* __restrict__ diag2,
        const float* __restrict__ rw1, const float* __restrict__ rb1,
        const float* __restrict__ rw2, const float* __restrict__ rb2,
        float* __restrict__ out) {
    __shared__ float W1s[1024], W2s[512];
    __shared__ float uls[8][128];
    __shared__ float ufin[128], x1ls[128];
    __shared__ int isLast;
    for (int i = threadIdx.x; i < 1024; i += 256) W1s[i] = W1[i];
    for (int i = threadIdx.x; i < 512; i += 256) W2s[i] = W2[i];
    int n1c = tails[2]; if (n1c > N1_CAP) n1c = N1_CAP;
    int g = threadIdx.x >> 5, t32 = threadIdx.x & 31;
    int b = t32 >> 3, c4 = t32 & 7;
    const float4* t1f4 = (const float4*)t1C;
    for (int s = blockIdx.x; s < n1c; s += gridDim.x) {
        int L = wi_cntC[s]; if (L > WIDEG) L = WIDEG;
        const int2* wip = wi_pairs + (size_t)s * WIDEG;
        float4 acc = make_float4(0.f, 0.f, 0.f, 0.f);
        for (int e = g; e < L; e += 8) {
            int2 pe = wip[e];
            int rs = rslot[pe.x];
            float coef = __int_as_float(pe.y);        // diag1 already folded
            if (rs >= 0 && rs < RS_CAP) {
                float4 tv = t1f4[(size_t)rs * 32 + b * 8 + c4];
                acc.x += coef * tv.x; acc.y += coef * tv.y;
                acc.z += coef * tv.z; acc.w += coef * tv.w;
            }
        }
        float* up = &uls[g][b * 32 + c4 * 4];
        up[0] = acc.x; up[1] = acc.y; up[2] = acc.z; up[3] = acc.w;
        __syncthreads();
        if (threadIdx.x < 128) {
            float sum = 0.f;
#pragma unroll
            for (int gg = 0; gg < 8; ++gg) sum += uls[gg][threadIdx.x];
            ufin[threadIdx.x] = sum;
        }
        __syncthreads();
        if (threadIdx.x < 128) {
            int bb = threadIdx.x >> 5, c = threadIdx.x & 31;
            const float* ur = &ufin[bb * 32];
            float o = 0.f;
#pragma unroll
            for (int k = 0; k < 32; ++k) o += ur[k] * W1s[k * 32 + c];
            x1ls[threadIdx.x] = o > 0.f ? o : NEG_SLOPE * o;
        }
        __syncthreads();
        if (threadIdx.x < 64) {
            int bb = threadIdx.x >> 4, c = threadIdx.x & 15;
            const float* xr = &x1ls[bb * 32];
            float o = 0.f;
#pragma unroll
            for (int k = 0; k < 32; ++k) o += xr[k] * W2s[k * 16 + c];
            h2C[(size_t)s * 64 + bb * 16 + c] = o;
        }
        __syncthreads();
    }

    // -------- last-finisher: t2 gather + x2 + heads (256 threads) --------
    __threadfence();                              // release h2C writes
    if (threadIdx.x == 0) {
        int old = atomicAdd(&tails[5], 1);
        isLast = (old == (int)gridDim.x - 1);
    }
    __syncthreads();
    if (!isLast) return;
    __threadfence();                              // acquire other blocks' h2C

    __shared__ float red0[4][64], red1[4][64], xs[2][64];
    // phase 1: t2 over r2 slots [0, r2c), 16 float4-lanes per slot
    int r2c = tails[4]; if (r2c > R2_CAP) r2c = R2_CAP;
    for (int idx = threadIdx.x; idx < r2c * 16; idx += 256) {
        int s = idx >> 4;
        int rem = idx & 15;
        int cc4 = rem & 3;
        int bb = rem >> 2;
        int L = w_cntC[s]; if (L > WDEG) L = WDEG;
        const int2* pr = w_pairs + (size_t)s * WDEG;
        const float4* sb = (const float4*)h2C + bb * 4 + cc4;
        float4 acc = make_float4(0.f, 0.f, 0.f, 0.f);
        for (int i = 0; i < L; ++i) {
            int2 p = pr[i];
            int hs = n1slot[p.x];               // col is n1 by construction
            float v = __int_as_float(p.y);
            if (hs >= 0 && hs < N1_CAP) {
                float4 sv = sb[(size_t)hs * 16];
                acc.x += v * sv.x; acc.y += v * sv.y; acc.z += v * sv.z; acc.w += v * sv.w;
            }
        }
        ((float4*)t2C)[(size_t)s * 16 + bb * 4 + cc4] = acc;
    }
    __syncthreads();

    // phase 2: x2 accumulation, edge-parallel across 4 groups of 64 lanes
    int cnt = tails[0]; if (cnt > X2_CAP) cnt = X2_CAP;
    int g2 = threadIdx.x >> 6, l = threadIdx.x & 63;
    int bb = l >> 4, cix = l & 15;
    float a0 = 0.f, a1 = 0.f;
    for (int i = g2; i < cnt; i += 4) {
        int2 rec = x2list[i];
        int col = rec.x >> 1;
        int s = rslot[col];
        float coef = __int_as_float(rec.y) * diag2[col];
        float v = (s >= 0 && s < R2_CAP) ? t2C[(size_t)s * 64 + bb * 16 + cix] * coef : 0.f;
        if (rec.x & 1) a1 += v; else a0 += v;
    }
    red0[g2][l] = a0; red1[g2][l] = a1;
    __syncthreads();
    if (threadIdx.x < 64) {
        float s0 = 0.f, s1 = 0.f;
#pragma unroll
        for (int gg = 0; gg < 4; ++gg) { s0 += red0[gg][threadIdx.x]; s1 += red1[gg][threadIdx.x]; }
        xs[0][threadIdx.x] = s0; xs[1][threadIdx.x] = s1;
    }
    __syncthreads();
    if (threadIdx.x < 8) {
        int bo = threadIdx.x >> 1, which = threadIdx.x & 1;
        const float* w = which ? rw2 : rw1;
        float acc = which ? rb2[0] : rb1[0];
        for (int k = 0; k < 16; ++k) {
            float xv = xs[which][bo * 16 + k];
            xv = xv > 0.f ? xv : NEG_SLOPE * xv;
            acc += xv * w[k];
        }
        out[bo * 2 + which] = acc;
    }
}

extern "C" void kernel_launch(void* const* d_in, const int* in_sizes, int n_in,
                              void* d_out, int out_size, void* d_ws, size_t ws_size,
                              hipStream_t stream) {
    const int*   w_rows  = (const int*)d_in[0];
    const int*   w_cols  = ((const int*)d_in[0]) + E;
    const float* w_val   = (const float*)d_in[1];
    const int*   wi_rows = (const int*)d_in[2];
    const int*   wi_cols = ((const int*)d_in[2]) + E;
    const float* wi_val  = (const float*)d_in[3];
    const float* x       = (const float*)d_in[4];
    const float* W1      = (const float*)d_in[5];
    const float* diag1   = (const float*)d_in[6];
    const float* W2      = (const float*)d_in[7];
    const float* diag2   = (const float*)d_in[8];
    const float* rw1     = (const float*)d_in[9];
    const float* rb1     = (const float*)d_in[10];
    const float* rw2     = (const float*)d_in[11];
    const float* rb2     = (const float*)d_in[12];
    float* out = (float*)d_out;

    // ---------------- workspace layout (~56 MB) ----------------
    float* t1C = (float*)d_ws;                       // [RS_CAP][128] (25.2 MB)
    float* h2C = t1C + (size_t)RS_CAP * 128;         // [N1_CAP][64]  (1 MB)
    float* t2C = h2C + (size_t)N1_CAP * 64;          // [R2_CAP][64]  (1 MB)
    int* ip = (int*)(t2C + (size_t)R2_CAP * 64);
    // zeroed block (contiguous, ZWORDS words):
    int* w_cntC  = ip; ip += RS_CAP;
    int* wi_cntC = ip; ip += N1_CAP;
    unsigned* bitsRS = (unsigned*)ip; ip += RBW;
    unsigned* bitsN1 = (unsigned*)ip; ip += NBW;
    int* tails = ip; ip += 8;
    // un-zeroed:
    int* rslot  = ip; ip += R;
    int* n1slot = ip; ip += N;
    int2* x2list = (int2*)ip; ip += 2 * X2_CAP;
    int2* w_pairs  = (int2*)ip; ip += 2 * (size_t)RS_CAP * WDEG;   // 25.2 MB
    int2* wi_pairs = (int2*)ip; ip += 2 * (size_t)N1_CAP * WIDEG;  // 3.1 MB

    const int e4 = E / 4;
    const int blk = 256;
    const int scanGrid = (e4 + blk - 1) / blk;

    (void)hipMemsetAsync(w_cntC, 0, (size_t)ZWORDS * sizeof(int), stream);

    scanA<<<scanGrid, blk, 0, stream>>>((const int4*)wi_rows, (const int4*)wi_cols,
                                        (const float4*)wi_val, bitsRS, rslot,
                                        x2list, tails, e4);
    scanB<<<scanGrid, blk, 0, stream>>>((const int4*)w_rows, (const int4*)w_cols,
                                        bitsRS, bitsN1, n1slot, tails, e4);
    scanC<<<scanGrid, blk, 0, stream>>>((const int4*)wi_rows, (const int4*)wi_cols,
                                        (const float4*)wi_val, diag1, bitsN1, n1slot,
                                        bitsRS, rslot, wi_cntC, wi_pairs, tails, e4);
    scanD<<<scanGrid, blk, 0, stream>>>((const int4*)w_rows, (const int4*)w_cols,
                                        (const float4*)w_val, bitsRS, rslot,
                                        w_cntC, w_pairs, e4);
    gather_t1<<<2048, blk, 0, stream>>>(x, t1C, w_cntC, w_pairs, tails);
    x1mlp<<<1024, blk, 0, stream>>>(W1, W2, tails, wi_cntC, wi_pairs, rslot, t1C, h2C,
                                    w_cntC, w_pairs, n1slot, t2C, x2list, diag2,
                                    rw1, rb1, rw2, rb2, out);
}

// Round 9
// 260.633 us; speedup vs baseline: 1.4778x; 1.4778x over previous
//
#include <hip/hip_runtime.h>

#define NEG_SLOPE 0.2f

static const int B = 4, N = 50000, R = 100000, E = 1600000;
static const int X2_CAP = 4096;     // x2 edge records (expected ~64)
static const int R2_CAP = 4096;     // r2 rows (expected ~64)
static const int N1_CAP = 4096;     // n1 nodes (expected ~1k)
static const int RS_CAP = 49152;    // row slots, r2 + r1 (expected ~28k)
static const int WDEG  = 64;        // w-CSR slab per slot (mean deg 16)
static const int WIDEG = 96;        // wi-CSR slab per n1 slot (mean deg 32)
static const int RBW = 3200;        // bit-words for R rows
static const int NBW = 1600;        // bit-words for N nodes
static const int ZWORDS = RS_CAP + N1_CAP + RBW + NBW + 8;
// tails: [0]=x2tail [1]=unused [2]=n1tail [3]=slotTail [4]=r2c snapshot

// ---- scanA: wi edges with row>=N-2 -> x2list + r2 rows get slots [0,r2c) ----
__global__ void scanA(const int4* __restrict__ wi_rows4, const int4* __restrict__ wi_cols4,
                      const float4* __restrict__ wi_val4,
                      unsigned* __restrict__ bitsRS, int* __restrict__ rslot,
                      int2* __restrict__ x2list, int* __restrict__ tails, int e4) {
    int i = blockIdx.x * blockDim.x + threadIdx.x;
    if (i >= e4) return;
    int4 r = wi_rows4[i];
    int rr[4] = {r.x, r.y, r.z, r.w};
    bool any = false;
#pragma unroll
    for (int j = 0; j < 4; ++j) any = any || (rr[j] >= N - 2);
    if (!any) return;
    int4 c = wi_cols4[i];
    float4 v = wi_val4[i];
    int cc[4] = {c.x, c.y, c.z, c.w};
    float vv[4] = {v.x, v.y, v.z, v.w};
#pragma unroll
    for (int j = 0; j < 4; ++j) {
        if (rr[j] >= N - 2) {
            int col = cc[j];
            unsigned m = 1u << (col & 31);
            unsigned old = atomicOr(&bitsRS[col >> 5], m);
            if (!(old & m)) {
                int s = atomicAdd(&tails[3], 1);   // ~64 winners: negligible
                if (s < RS_CAP) rslot[col] = s;
            }
            int q = atomicAdd(&tails[0], 1);
            if (q < X2_CAP)
                x2list[q] = make_int2(col * 2 + (rr[j] - (N - 2)),
                                      __float_as_int(vv[j]));
        }
    }
}

// ---- scanB: w edges with row in r2 (bitsRS) -> n1 set, slot via block-agg ----
__global__ void scanB(const int4* __restrict__ w_rows4, const int4* __restrict__ w_cols4,
                      const unsigned* __restrict__ bitsRS, unsigned* __restrict__ bitsN1,
                      int* __restrict__ n1slot, int* __restrict__ tails, int e4) {
    __shared__ int lcount, gbase;
    __shared__ int buf[1024];
    if (threadIdx.x == 0) {
        lcount = 0;
        if (blockIdx.x == 0) tails[4] = tails[3];   // snapshot r2c
    }
    __syncthreads();
    int lane = threadIdx.x & 63;
    int i = blockIdx.x * blockDim.x + threadIdx.x;
    int4 r = make_int4(-1, -1, -1, -1);
    if (i < e4) r = w_rows4[i];
    int rr[4] = {r.x, r.y, r.z, r.w};
    unsigned fb[4];
#pragma unroll
    for (int j = 0; j < 4; ++j)
        fb[j] = (rr[j] >= 0) ? ((bitsRS[rr[j] >> 5] >> (rr[j] & 31)) & 1u) : 0u;
    bool anyf = (fb[0] | fb[1] | fb[2] | fb[3]) != 0u;
    int4 c = make_int4(0, 0, 0, 0);
    if (anyf) c = w_cols4[i];
    int cc[4] = {c.x, c.y, c.z, c.w};
#pragma unroll
    for (int j = 0; j < 4; ++j) {
        bool isnew = false;
        int n = 0;
        if (fb[j]) {
            n = cc[j];
            unsigned m = 1u << (n & 31);
            unsigned old = atomicOr(&bitsN1[n >> 5], m);
            isnew = (old & m) == 0u;
        }
        unsigned long long mb = __ballot(isnew);
        if (mb) {
            int leader = __ffsll(mb) - 1;
            int b0 = 0;
            if (lane == leader) b0 = atomicAdd(&lcount, __popcll(mb));
            b0 = __shfl(b0, leader);
            if (isnew) {
                int p = b0 + __popcll(mb & ((1ull << lane) - 1));
                if (p < 1024) buf[p] = n;
            }
        }
    }
    __syncthreads();
    int lc = lcount; if (lc > 1024) lc = 1024;
    if (threadIdx.x == 0 && lc > 0) gbase = atomicAdd(&tails[2], lc);
    __syncthreads();
    for (int t = threadIdx.x; t < lc; t += blockDim.x) {
        int slot = gbase + t;
        if (slot < N1_CAP) n1slot[buf[t]] = slot;
    }
}

// ---- scanC: wi edges with node-row in n1 -> wi-place + r1 slots (block-agg) ----
__global__ void scanC(const int4* __restrict__ wi_rows4, const int4* __restrict__ wi_cols4,
                      const float4* __restrict__ wi_val4, const float* __restrict__ diag1,
                      const unsigned* __restrict__ bitsN1, const int* __restrict__ n1slot,
                      unsigned* __restrict__ bitsRS, int* __restrict__ rslot,
                      int* __restrict__ wi_cntC, int2* __restrict__ wi_pairs,
                      int* __restrict__ tails, int e4) {
    __shared__ int lcount, gbase;
    __shared__ int buf[1024];
    if (threadIdx.x == 0) lcount = 0;
    __syncthreads();
    int lane = threadIdx.x & 63;
    int i = blockIdx.x * blockDim.x + threadIdx.x;
    int4 r = make_int4(-1, -1, -1, -1);
    if (i < e4) r = wi_rows4[i];
    int rr[4] = {r.x, r.y, r.z, r.w};
    unsigned fb[4];
#pragma unroll
    for (int j = 0; j < 4; ++j)
        fb[j] = (rr[j] >= 0) ? ((bitsN1[rr[j] >> 5] >> (rr[j] & 31)) & 1u) : 0u;
    bool anyf = (fb[0] | fb[1] | fb[2] | fb[3]) != 0u;
    int4 c = make_int4(0, 0, 0, 0);
    float4 v = make_float4(0.f, 0.f, 0.f, 0.f);
    if (anyf) { c = wi_cols4[i]; v = wi_val4[i]; }
    int cc[4] = {c.x, c.y, c.z, c.w};
    float vv[4] = {v.x, v.y, v.z, v.w};
#pragma unroll
    for (int j = 0; j < 4; ++j) {
        bool isnew = false;
        int col = 0;
        if (fb[j]) {
            col = cc[j];
            float cf = vv[j] * diag1[col];
            int slot = n1slot[rr[j]];
            if (slot >= 0 && slot < N1_CAP) {
                int pos = atomicAdd(&wi_cntC[slot], 1);
                if (pos < WIDEG)
                    wi_pairs[(size_t)slot * WIDEG + pos] =
                        make_int2(col, __float_as_int(cf));
            }
            unsigned m = 1u << (col & 31);
            unsigned old = atomicOr(&bitsRS[col >> 5], m);
            isnew = (old & m) == 0u;
        }
        unsigned long long mb = __ballot(isnew);
        if (mb) {
            int leader = __ffsll(mb) - 1;
            int b0 = 0;
            if (lane == leader) b0 = atomicAdd(&lcount, __popcll(mb));
            b0 = __shfl(b0, leader);
            if (isnew) {
                int p = b0 + __popcll(mb & ((1ull << lane) - 1));
                if (p < 1024) buf[p] = col;
            }
        }
    }
    __syncthreads();
    int lc = lcount; if (lc > 1024) lc = 1024;
    if (threadIdx.x == 0 && lc > 0) gbase = atomicAdd(&tails[3], lc);
    __syncthreads();
    for (int t = threadIdx.x; t < lc; t += blockDim.x) {
        int s = gbase + t;
        if (s < RS_CAP) rslot[buf[t]] = s;
    }
}

// ---- scanD: w edges with slotted row (r1|r2) -> compact w-slab place ----
__global__ void scanD(const int4* __restrict__ w_rows4, const int4* __restrict__ w_cols4,
                      const float4* __restrict__ w_val4,
                      const unsigned* __restrict__ bitsRS, const int* __restrict__ rslot,
                      int* __restrict__ w_cntC, int2* __restrict__ w_pairs, int e4) {
    int i = blockIdx.x * blockDim.x + threadIdx.x;
    if (i >= e4) return;
    int4 r = w_rows4[i];
    int rr[4] = {r.x, r.y, r.z, r.w};
    unsigned fb[4];
#pragma unroll
    for (int j = 0; j < 4; ++j) fb[j] = (bitsRS[rr[j] >> 5] >> (rr[j] & 31)) & 1u;
    if (!(fb[0] | fb[1] | fb[2] | fb[3])) return;
    int4 c = w_cols4[i];
    float4 v = w_val4[i];
    int cc[4] = {c.x, c.y, c.z, c.w};
    float vv[4] = {v.x, v.y, v.z, v.w};
    int s[4];
#pragma unroll
    for (int j = 0; j < 4; ++j) s[j] = fb[j] ? rslot[rr[j]] : RS_CAP;
#pragma unroll
    for (int j = 0; j < 4; ++j) {
        if (fb[j] && s[j] >= 0 && s[j] < RS_CAP) {
            int pos = atomicAdd(&w_cntC[s[j]], 1);
            if (pos < WDEG)
                w_pairs[(size_t)s[j] * WDEG + pos] =
                    make_int2(cc[j], __float_as_int(vv[j]));
        }
    }
}

// ---- gather_t1: per slot, t1C[s] = sum_w v * x[col]  (32 threads/slot) ----
__global__ void gather_t1(const float* __restrict__ x, float* __restrict__ t1C,
                          const int* __restrict__ w_cntC, const int2* __restrict__ w_pairs,
                          const int* __restrict__ tails) {
    int tot = tails[3]; if (tot > RS_CAP) tot = RS_CAP;
    int total = tot * 32;
    int gstride = gridDim.x * blockDim.x;
    for (int idx = blockIdx.x * blockDim.x + threadIdx.x; idx < total; idx += gstride) {
        int s = idx >> 5;
        int rem = idx & 31;
        int c4 = rem & 7;
        int b = rem >> 3;
        int L = w_cntC[s]; if (L > WDEG) L = WDEG;
        const int2* pr = w_pairs + (size_t)s * WDEG;
        const float4* sb = (const float4*)x + (size_t)b * N * 8 + c4;
        float4 acc = make_float4(0.f, 0.f, 0.f, 0.f);
        int i = 0;
        int L4 = L & ~3;
        for (; i < L4; i += 4) {
            int2 p0 = pr[i + 0];
            int2 p1 = pr[i + 1];
            int2 p2 = pr[i + 2];
            int2 p3 = pr[i + 3];
            float4 s0 = sb[(size_t)p0.x * 8];
            float4 s1 = sb[(size_t)p1.x * 8];
            float4 s2 = sb[(size_t)p2.x * 8];
            float4 s3 = sb[(size_t)p3.x * 8];
            float v0 = __int_as_float(p0.y), v1 = __int_as_float(p1.y);
            float v2 = __int_as_float(p2.y), v3 = __int_as_float(p3.y);
            acc.x += v0 * s0.x + v1 * s1.x + v2 * s2.x + v3 * s3.x;
            acc.y += v0 * s0.y + v1 * s1.y + v2 * s2.y + v3 * s3.y;
            acc.z += v0 * s0.z + v1 * s1.z + v2 * s2.z + v3 * s3.z;
            acc.w += v0 * s0.w + v1 * s1.w + v2 * s2.w + v3 * s3.w;
        }
        for (; i < L; ++i) {
            int2 p = pr[i];
            float4 sv = sb[(size_t)p.x * 8];
            float v = __int_as_float(p.y);
            acc.x += v * sv.x; acc.y += v * sv.y; acc.z += v * sv.z; acc.w += v * sv.w;
        }
        ((float4*)t1C)[(size_t)s * 32 + b * 8 + c4] = acc;
    }
}

// ---- x1mlp: per n1 slot, u = wi-agg(t1C); h2C = lrelu(u@W1)@W2 ----
__global__ void __launch_bounds__(256) x1mlp(
        const float* __restrict__ W1, const float* __restrict__ W2,
        const int* __restrict__ tails,
        const int* __restrict__ wi_cntC, const int2* __restrict__ wi_pairs,
        const int* __restrict__ rslot, const float* __restrict__ t1C,
        float* __restrict__ h2C) {
    __shared__ float W1s[1024], W2s[512];
    __shared__ float uls[8][128];
    __shared__ float ufin[128], x1ls[128];
    for (int i = threadIdx.x; i < 1024; i += 256) W1s[i] = W1[i];
    for (int i = threadIdx.x; i < 512; i += 256) W2s[i] = W2[i];
    int n1c = tails[2]; if (n1c > N1_CAP) n1c = N1_CAP;
    int g = threadIdx.x >> 5, t32 = threadIdx.x & 31;
    int b = t32 >> 3, c4 = t32 & 7;
    const float4* t1f4 = (const float4*)t1C;
    for (int s = blockIdx.x; s < n1c; s += gridDim.x) {
        int L = wi_cntC[s]; if (L > WIDEG) L = WIDEG;
        const int2* wip = wi_pairs + (size_t)s * WIDEG;
        float4 acc = make_float4(0.f, 0.f, 0.f, 0.f);
        for (int e = g; e < L; e += 8) {
            int2 pe = wip[e];
            int rs = rslot[pe.x];
            float coef = __int_as_float(pe.y);        // diag1 already folded
            if (rs >= 0 && rs < RS_CAP) {
                float4 tv = t1f4[(size_t)rs * 32 + b * 8 + c4];
                acc.x += coef * tv.x; acc.y += coef * tv.y;
                acc.z += coef * tv.z; acc.w += coef * tv.w;
            }
        }
        float* up = &uls[g][b * 32 + c4 * 4];
        up[0] = acc.x; up[1] = acc.y; up[2] = acc.z; up[3] = acc.w;
        __syncthreads();
        if (threadIdx.x < 128) {
            float sum = 0.f;
#pragma unroll
            for (int gg = 0; gg < 8; ++gg) sum += uls[gg][threadIdx.x];
            ufin[threadIdx.x] = sum;
        }
        __syncthreads();
        if (threadIdx.x < 128) {
            int bb = threadIdx.x >> 5, c = threadIdx.x & 31;
            const float* ur = &ufin[bb * 32];
            float o = 0.f;
#pragma unroll
            for (int k = 0; k < 32; ++k) o += ur[k] * W1s[k * 32 + c];
            x1ls[threadIdx.x] = o > 0.f ? o : NEG_SLOPE * o;
        }
        __syncthreads();
        if (threadIdx.x < 64) {
            int bb = threadIdx.x >> 4, c = threadIdx.x & 15;
            const float* xr = &x1ls[bb * 32];
            float o = 0.f;
#pragma unroll
            for (int k = 0; k < 32; ++k) o += xr[k] * W2s[k * 16 + c];
            h2C[(size_t)s * 64 + bb * 16 + c] = o;
        }
        __syncthreads();
    }
}

// ---- t2 gather (r2 slots) + x2 accumulation + heads, ONE block of 1024 ----
__global__ void t2x2heads(const float* __restrict__ h2C,
                          const int* __restrict__ w_cntC, const int2* __restrict__ w_pairs,
                          const int* __restrict__ n1slot, const int* __restrict__ rslot,
                          const int* __restrict__ tails, float* __restrict__ t2C,
                          const int2* __restrict__ x2list,
                          const float* __restrict__ diag2,
                          const float* __restrict__ rw1, const float* __restrict__ rb1,
                          const float* __restrict__ rw2, const float* __restrict__ rb2,
                          float* __restrict__ out) {
    // phase 1: t2 over r2 slots [0, r2c), 16 float4-lanes per slot
    int r2c = tails[4]; if (r2c > R2_CAP) r2c = R2_CAP;
    for (int idx = threadIdx.x; idx < r2c * 16; idx += blockDim.x) {
        int s = idx >> 4;
        int rem = idx & 15;
        int c4 = rem & 3;
        int b = rem >> 2;
        int L = w_cntC[s]; if (L > WDEG) L = WDEG;
        const int2* pr = w_pairs + (size_t)s * WDEG;
        const float4* sb = (const float4*)h2C + b * 4 + c4;
        float4 acc = make_float4(0.f, 0.f, 0.f, 0.f);
        for (int i = 0; i < L; ++i) {
            int2 p = pr[i];
            int hs = n1slot[p.x];               // col is n1 by construction
            float v = __int_as_float(p.y);
            if (hs >= 0 && hs < N1_CAP) {
                float4 sv = sb[(size_t)hs * 16];
                acc.x += v * sv.x; acc.y += v * sv.y; acc.z += v * sv.z; acc.w += v * sv.w;
            }
        }
        ((float4*)t2C)[(size_t)s * 16 + b * 4 + c4] = acc;
    }
    __syncthreads();

    // phase 2: x2 accumulation, edge-parallel across 16 groups of 64 lanes
    int cnt = tails[0]; if (cnt > X2_CAP) cnt = X2_CAP;
    int g = threadIdx.x >> 6, l = threadIdx.x & 63;
    int b = l >> 4, c = l & 15;
    float a0 = 0.f, a1 = 0.f;
    for (int i = g; i < cnt; i += 16) {
        int2 rec = x2list[i];
        int col = rec.x >> 1;
        int s = rslot[col];
        float coef = __int_as_float(rec.y) * diag2[col];
        float v = (s >= 0 && s < R2_CAP) ? t2C[(size_t)s * 64 + b * 16 + c] * coef : 0.f;
        if (rec.x & 1) a1 += v; else a0 += v;
    }
    __shared__ float red0[16][64], red1[16][64], xs[2][64];
    red0[g][l] = a0; red1[g][l] = a1;
    __syncthreads();
    if (threadIdx.x < 64) {
        float s0 = 0.f, s1 = 0.f;
#pragma unroll
        for (int gg = 0; gg < 16; ++gg) { s0 += red0[gg][threadIdx.x]; s1 += red1[gg][threadIdx.x]; }
        xs[0][threadIdx.x] = s0; xs[1][threadIdx.x] = s1;
    }
    __syncthreads();
    if (threadIdx.x < 8) {
        int bb = threadIdx.x >> 1, which = threadIdx.x & 1;
        const float* w = which ? rw2 : rw1;
        float acc = which ? rb2[0] : rb1[0];
        for (int k = 0; k < 16; ++k) {
            float xv = xs[which][bb * 16 + k];
            xv = xv > 0.f ? xv : NEG_SLOPE * xv;
            acc += xv * w[k];
        }
        out[bb * 2 + which] = acc;
    }
}

extern "C" void kernel_launch(void* const* d_in, const int* in_sizes, int n_in,
                              void* d_out, int out_size, void* d_ws, size_t ws_size,
                              hipStream_t stream) {
    const int*   w_rows  = (const int*)d_in[0];
    const int*   w_cols  = ((const int*)d_in[0]) + E;
    const float* w_val   = (const float*)d_in[1];
    const int*   wi_rows = (const int*)d_in[2];
    const int*   wi_cols = ((const int*)d_in[2]) + E;
    const float* wi_val  = (const float*)d_in[3];
    const float* x       = (const float*)d_in[4];
    const float* W1      = (const float*)d_in[5];
    const float* diag1   = (const float*)d_in[6];
    const float* W2      = (const float*)d_in[7];
    const float* diag2   = (const float*)d_in[8];
    const float* rw1     = (const float*)d_in[9];
    const float* rb1     = (const float*)d_in[10];
    const float* rw2     = (const float*)d_in[11];
    const float* rb2     = (const float*)d_in[12];
    float* out = (float*)d_out;

    // ---------------- workspace layout (~56 MB) ----------------
    float* t1C = (float*)d_ws;                       // [RS_CAP][128] (25.2 MB)
    float* h2C = t1C + (size_t)RS_CAP * 128;         // [N1_CAP][64]  (1 MB)
    float* t2C = h2C + (size_t)N1_CAP * 64;          // [R2_CAP][64]  (1 MB)
    int* ip = (int*)(t2C + (size_t)R2_CAP * 64);
    // zeroed block (contiguous, ZWORDS words):
    int* w_cntC  = ip; ip += RS_CAP;
    int* wi_cntC = ip; ip += N1_CAP;
    unsigned* bitsRS = (unsigned*)ip; ip += RBW;
    unsigned* bitsN1 = (unsigned*)ip; ip += NBW;
    int* tails = ip; ip += 8;
    // un-zeroed:
    int* rslot  = ip; ip += R;
    int* n1slot = ip; ip += N;
    int2* x2list = (int2*)ip; ip += 2 * X2_CAP;
    int2* w_pairs  = (int2*)ip; ip += 2 * (size_t)RS_CAP * WDEG;   // 25.2 MB
    int2* wi_pairs = (int2*)ip; ip += 2 * (size_t)N1_CAP * WIDEG;  // 3.1 MB

    const int e4 = E / 4;
    const int blk = 256;
    const int scanGrid = (e4 + blk - 1) / blk;

    (void)hipMemsetAsync(w_cntC, 0, (size_t)ZWORDS * sizeof(int), stream);

    scanA<<<scanGrid, blk, 0, stream>>>((const int4*)wi_rows, (const int4*)wi_cols,
                                        (const float4*)wi_val, bitsRS, rslot,
                                        x2list, tails, e4);
    scanB<<<scanGrid, blk, 0, stream>>>((const int4*)w_rows, (const int4*)w_cols,
                                        bitsRS, bitsN1, n1slot, tails, e4);
    scanC<<<scanGrid, blk, 0, stream>>>((const int4*)wi_rows, (const int4*)wi_cols,
                                        (const float4*)wi_val, diag1, bitsN1, n1slot,
                                        bitsRS, rslot, wi_cntC, wi_pairs, tails, e4);
    scanD<<<scanGrid, blk, 0, stream>>>((const int4*)w_rows, (const int4*)w_cols,
                                        (const float4*)w_val, bitsRS, rslot,
                                        w_cntC, w_pairs, e4);
    gather_t1<<<2048, blk, 0, stream>>>(x, t1C, w_cntC, w_pairs, tails);
    x1mlp<<<1024, blk, 0, stream>>>(W1, W2, tails, wi_cntC, wi_pairs, rslot, t1C, h2C);
    t2x2heads<<<1, 1024, 0, stream>>>(h2C, w_cntC, w_pairs, n1slot, rslot, tails,
                                      t2C, x2list, diag2, rw1, rb1, rw2, rb2, out);
}

// Round 10
// 241.883 us; speedup vs baseline: 1.5923x; 1.0775x over previous
//
#include <hip/hip_runtime.h>

#define NEG_SLOPE 0.2f

static const int B = 4, N = 50000, R = 100000, E = 1600000;
static const int X2_CAP = 4096;     // x2 edge records (expected ~64)
static const int R2_CAP = 4096;     // r2 rows (expected ~64)
static const int N1_CAP = 4096;     // n1 nodes (expected ~1k)
static const int RS_CAP = 49152;    // row slots, r2 + r1 (expected ~28k)
static const int WDEG  = 64;        // w-CSR slab per slot (mean deg 16)
static const int WIDEG = 96;        // wi-CSR slab per n1 slot (mean deg 32)
static const int RBW = 3200;        // bit-words for R rows
static const int NBW = 1600;        // bit-words for N nodes
static const int ZWORDS = RS_CAP + N1_CAP + RBW + NBW + 8;
// tails: [0]=x2tail [1]=unused [2]=n1tail [3]=slotTail [4]=r2c snapshot

// ---- scanA: wi edges with row>=N-2 -> x2list + r2 rows get slots [0,r2c) ----
__global__ void scanA(const int4* __restrict__ wi_rows4, const int4* __restrict__ wi_cols4,
                      const float4* __restrict__ wi_val4,
                      unsigned* __restrict__ bitsRS, int* __restrict__ rslot,
                      int2* __restrict__ x2list, int* __restrict__ tails, int e4) {
    int i = blockIdx.x * blockDim.x + threadIdx.x;
    if (i >= e4) return;
    int4 r = wi_rows4[i];
    int rr[4] = {r.x, r.y, r.z, r.w};
    bool any = false;
#pragma unroll
    for (int j = 0; j < 4; ++j) any = any || (rr[j] >= N - 2);
    if (!any) return;
    int4 c = wi_cols4[i];
    float4 v = wi_val4[i];
    int cc[4] = {c.x, c.y, c.z, c.w};
    float vv[4] = {v.x, v.y, v.z, v.w};
#pragma unroll
    for (int j = 0; j < 4; ++j) {
        if (rr[j] >= N - 2) {
            int col = cc[j];
            unsigned m = 1u << (col & 31);
            unsigned old = atomicOr(&bitsRS[col >> 5], m);
            if (!(old & m)) {
                int s = atomicAdd(&tails[3], 1);   // ~64 winners: negligible
                if (s < RS_CAP) rslot[col] = s;
            }
            int q = atomicAdd(&tails[0], 1);
            if (q < X2_CAP)
                x2list[q] = make_int2(col * 2 + (rr[j] - (N - 2)),
                                      __float_as_int(vv[j]));
        }
    }
}

// ---- scanB: w edges with row in r2 (bitsRS) -> n1 set, slot via block-agg ----
__global__ void scanB(const int4* __restrict__ w_rows4, const int4* __restrict__ w_cols4,
                      const unsigned* __restrict__ bitsRS, unsigned* __restrict__ bitsN1,
                      int* __restrict__ n1slot, int* __restrict__ tails, int e4) {
    __shared__ int lcount, gbase;
    __shared__ int buf[1024];
    if (threadIdx.x == 0) {
        lcount = 0;
        if (blockIdx.x == 0) tails[4] = tails[3];   // snapshot r2c
    }
    __syncthreads();
    int lane = threadIdx.x & 63;
    int i = blockIdx.x * blockDim.x + threadIdx.x;
    int4 r = make_int4(-1, -1, -1, -1);
    if (i < e4) r = w_rows4[i];
    int rr[4] = {r.x, r.y, r.z, r.w};
    unsigned fb[4];
#pragma unroll
    for (int j = 0; j < 4; ++j)
        fb[j] = (rr[j] >= 0) ? ((bitsRS[rr[j] >> 5] >> (rr[j] & 31)) & 1u) : 0u;
    bool anyf = (fb[0] | fb[1] | fb[2] | fb[3]) != 0u;
    int4 c = make_int4(0, 0, 0, 0);
    if (anyf) c = w_cols4[i];
    int cc[4] = {c.x, c.y, c.z, c.w};
#pragma unroll
    for (int j = 0; j < 4; ++j) {
        bool isnew = false;
        int n = 0;
        if (fb[j]) {
            n = cc[j];
            unsigned m = 1u << (n & 31);
            unsigned old = atomicOr(&bitsN1[n >> 5], m);
            isnew = (old & m) == 0u;
        }
        unsigned long long mb = __ballot(isnew);
        if (mb) {
            int leader = __ffsll(mb) - 1;
            int b0 = 0;
            if (lane == leader) b0 = atomicAdd(&lcount, __popcll(mb));
            b0 = __shfl(b0, leader);
            if (isnew) {
                int p = b0 + __popcll(mb & ((1ull << lane) - 1));
                if (p < 1024) buf[p] = n;
            }
        }
    }
    __syncthreads();
    int lc = lcount; if (lc > 1024) lc = 1024;
    if (threadIdx.x == 0 && lc > 0) gbase = atomicAdd(&tails[2], lc);
    __syncthreads();
    for (int t = threadIdx.x; t < lc; t += blockDim.x) {
        int slot = gbase + t;
        if (slot < N1_CAP) n1slot[buf[t]] = slot;
    }
}

// ---- scanC: wi edges with node-row in n1 -> wi-place + r1 slots (block-agg) ----
__global__ void scanC(const int4* __restrict__ wi_rows4, const int4* __restrict__ wi_cols4,
                      const float4* __restrict__ wi_val4, const float* __restrict__ diag1,
                      const unsigned* __restrict__ bitsN1, const int* __restrict__ n1slot,
                      unsigned* __restrict__ bitsRS, int* __restrict__ rslot,
                      int* __restrict__ wi_cntC, int2* __restrict__ wi_pairs,
                      int* __restrict__ tails, int e4) {
    __shared__ int lcount, gbase;
    __shared__ int buf[1024];
    if (threadIdx.x == 0) lcount = 0;
    __syncthreads();
    int lane = threadIdx.x & 63;
    int i = blockIdx.x * blockDim.x + threadIdx.x;
    int4 r = make_int4(-1, -1, -1, -1);
    if (i < e4) r = wi_rows4[i];
    int rr[4] = {r.x, r.y, r.z, r.w};
    unsigned fb[4];
#pragma unroll
    for (int j = 0; j < 4; ++j)
        fb[j] = (rr[j] >= 0) ? ((bitsN1[rr[j] >> 5] >> (rr[j] & 31)) & 1u) : 0u;
    bool anyf = (fb[0] | fb[1] | fb[2] | fb[3]) != 0u;
    int4 c = make_int4(0, 0, 0, 0);
    float4 v = make_float4(0.f, 0.f, 0.f, 0.f);
    if (anyf) { c = wi_cols4[i]; v = wi_val4[i]; }
    int cc[4] = {c.x, c.y, c.z, c.w};
    float vv[4] = {v.x, v.y, v.z, v.w};
#pragma unroll
    for (int j = 0; j < 4; ++j) {
        bool isnew = false;
        int col = 0;
        if (fb[j]) {
            col = cc[j];
            float cf = vv[j] * diag1[col];
            int slot = n1slot[rr[j]];
            if (slot >= 0 && slot < N1_CAP) {
                int pos = atomicAdd(&wi_cntC[slot], 1);
                if (pos < WIDEG)
                    wi_pairs[(size_t)slot * WIDEG + pos] =
                        make_int2(col, __float_as_int(cf));
            }
            unsigned m = 1u << (col & 31);
            unsigned old = atomicOr(&bitsRS[col >> 5], m);
            isnew = (old & m) == 0u;
        }
        unsigned long long mb = __ballot(isnew);
        if (mb) {
            int leader = __ffsll(mb) - 1;
            int b0 = 0;
            if (lane == leader) b0 = atomicAdd(&lcount, __popcll(mb));
            b0 = __shfl(b0, leader);
            if (isnew) {
                int p = b0 + __popcll(mb & ((1ull << lane) - 1));
                if (p < 1024) buf[p] = col;
            }
        }
    }
    __syncthreads();
    int lc = lcount; if (lc > 1024) lc = 1024;
    if (threadIdx.x == 0 && lc > 0) gbase = atomicAdd(&tails[3], lc);
    __syncthreads();
    for (int t = threadIdx.x; t < lc; t += blockDim.x) {
        int s = gbase + t;
        if (s < RS_CAP) rslot[buf[t]] = s;
    }
}

// ---- scanD: w edges with slotted row (r1|r2) -> compact w-slab place ----
__global__ void scanD(const int4* __restrict__ w_rows4, const int4* __restrict__ w_cols4,
                      const float4* __restrict__ w_val4,
                      const unsigned* __restrict__ bitsRS, const int* __restrict__ rslot,
                      int* __restrict__ w_cntC, int2* __restrict__ w_pairs, int e4) {
    int i = blockIdx.x * blockDim.x + threadIdx.x;
    if (i >= e4) return;
    int4 r = w_rows4[i];
    int rr[4] = {r.x, r.y, r.z, r.w};
    unsigned fb[4];
#pragma unroll
    for (int j = 0; j < 4; ++j) fb[j] = (bitsRS[rr[j] >> 5] >> (rr[j] & 31)) & 1u;
    if (!(fb[0] | fb[1] | fb[2] | fb[3])) return;
    int4 c = w_cols4[i];
    float4 v = w_val4[i];
    int cc[4] = {c.x, c.y, c.z, c.w};
    float vv[4] = {v.x, v.y, v.z, v.w};
    int s[4];
#pragma unroll
    for (int j = 0; j < 4; ++j) s[j] = fb[j] ? rslot[rr[j]] : RS_CAP;
#pragma unroll
    for (int j = 0; j < 4; ++j) {
        if (fb[j] && s[j] >= 0 && s[j] < RS_CAP) {
            int pos = atomicAdd(&w_cntC[s[j]], 1);
            if (pos < WDEG)
                w_pairs[(size_t)s[j] * WDEG + pos] =
                    make_int2(cc[j], __float_as_int(vv[j]));
        }
    }
}

// ---- gather_t1: per slot, t1C[s] = sum_w v * x[col]  (32 threads/slot) ----
__global__ void gather_t1(const float* __restrict__ x, float* __restrict__ t1C,
                          const int* __restrict__ w_cntC, const int2* __restrict__ w_pairs,
                          const int* __restrict__ tails) {
    int tot = tails[3]; if (tot > RS_CAP) tot = RS_CAP;
    int total = tot * 32;
    int gstride = gridDim.x * blockDim.x;
    for (int idx = blockIdx.x * blockDim.x + threadIdx.x; idx < total; idx += gstride) {
        int s = idx >> 5;
        int rem = idx & 31;
        int c4 = rem & 7;
        int b = rem >> 3;
        int L = w_cntC[s]; if (L > WDEG) L = WDEG;
        const int2* pr = w_pairs + (size_t)s * WDEG;
        const float4* sb = (const float4*)x + (size_t)b * N * 8 + c4;
        float4 acc = make_float4(0.f, 0.f, 0.f, 0.f);
        int i = 0;
        int L4 = L & ~3;
        for (; i < L4; i += 4) {
            int2 p0 = pr[i + 0];
            int2 p1 = pr[i + 1];
            int2 p2 = pr[i + 2];
            int2 p3 = pr[i + 3];
            float4 s0 = sb[(size_t)p0.x * 8];
            float4 s1 = sb[(size_t)p1.x * 8];
            float4 s2 = sb[(size_t)p2.x * 8];
            float4 s3 = sb[(size_t)p3.x * 8];
            float v0 = __int_as_float(p0.y), v1 = __int_as_float(p1.y);
            float v2 = __int_as_float(p2.y), v3 = __int_as_float(p3.y);
            acc.x += v0 * s0.x + v1 * s1.x + v2 * s2.x + v3 * s3.x;
            acc.y += v0 * s0.y + v1 * s1.y + v2 * s2.y + v3 * s3.y;
            acc.z += v0 * s0.z + v1 * s1.z + v2 * s2.z + v3 * s3.z;
            acc.w += v0 * s0.w + v1 * s1.w + v2 * s2.w + v3 * s3.w;
        }
        for (; i < L; ++i) {
            int2 p = pr[i];
            float4 sv = sb[(size_t)p.x * 8];
            float v = __int_as_float(p.y);
            acc.x += v * sv.x; acc.y += v * sv.y; acc.z += v * sv.z; acc.w += v * sv.w;
        }
        ((float4*)t1C)[(size_t)s * 32 + b * 8 + c4] = acc;
    }
}

// ---- x1mlp: per n1 slot, u = wi-agg(t1C); h2C = lrelu(u@W1)@W2 ----
__global__ void __launch_bounds__(256) x1mlp(
        const float* __restrict__ W1, const float* __restrict__ W2,
        const int* __restrict__ tails,
        const int* __restrict__ wi_cntC, const int2* __restrict__ wi_pairs,
        const int* __restrict__ rslot, const float* __restrict__ t1C,
        float* __restrict__ h2C) {
    __shared__ float W1s[1024], W2s[512];
    __shared__ float uls[8][128];
    __shared__ float ufin[128], x1ls[128];
    for (int i = threadIdx.x; i < 1024; i += 256) W1s[i] = W1[i];
    for (int i = threadIdx.x; i < 512; i += 256) W2s[i] = W2[i];
    int n1c = tails[2]; if (n1c > N1_CAP) n1c = N1_CAP;
    int g = threadIdx.x >> 5, t32 = threadIdx.x & 31;
    int b = t32 >> 3, c4 = t32 & 7;
    const float4* t1f4 = (const float4*)t1C;
    for (int s = blockIdx.x; s < n1c; s += gridDim.x) {
        int L = wi_cntC[s]; if (L > WIDEG) L = WIDEG;
        const int2* wip = wi_pairs + (size_t)s * WIDEG;
        float4 acc = make_float4(0.f, 0.f, 0.f, 0.f);
        for (int e = g; e < L; e += 8) {
            int2 pe = wip[e];
            int rs = rslot[pe.x];
            float coef = __int_as_float(pe.y);        // diag1 already folded
            if (rs >= 0 && rs < RS_CAP) {
                float4 tv = t1f4[(size_t)rs * 32 + b * 8 + c4];
                acc.x += coef * tv.x; acc.y += coef * tv.y;
                acc.z += coef * tv.z; acc.w += coef * tv.w;
            }
        }
        float* up = &uls[g][b * 32 + c4 * 4];
        up[0] = acc.x; up[1] = acc.y; up[2] = acc.z; up[3] = acc.w;
        __syncthreads();
        if (threadIdx.x < 128) {
            float sum = 0.f;
#pragma unroll
            for (int gg = 0; gg < 8; ++gg) sum += uls[gg][threadIdx.x];
            ufin[threadIdx.x] = sum;
        }
        __syncthreads();
        if (threadIdx.x < 128) {
            int bb = threadIdx.x >> 5, c = threadIdx.x & 31;
            const float* ur = &ufin[bb * 32];
            float o = 0.f;
#pragma unroll
            for (int k = 0; k < 32; ++k) o += ur[k] * W1s[k * 32 + c];
            x1ls[threadIdx.x] = o > 0.f ? o : NEG_SLOPE * o;
        }
        __syncthreads();
        if (threadIdx.x < 64) {
            int bb = threadIdx.x >> 4, c = threadIdx.x & 15;
            const float* xr = &x1ls[bb * 32];
            float o = 0.f;
#pragma unroll
            for (int k = 0; k < 32; ++k) o += xr[k] * W2s[k * 16 + c];
            h2C[(size_t)s * 64 + bb * 16 + c] = o;
        }
        __syncthreads();
    }
}

// ---- t2gather: per r2 slot, 256 threads = 16 edge-par x 16 (b,c4) lanes ----
__global__ void __launch_bounds__(256) t2gather(
        const float* __restrict__ h2C,
        const int* __restrict__ w_cntC, const int2* __restrict__ w_pairs,
        const int* __restrict__ n1slot, const int* __restrict__ tails,
        float* __restrict__ t2C) {
    __shared__ float4 red[16][16];
    int r2c = tails[4]; if (r2c > R2_CAP) r2c = R2_CAP;
    int e0 = threadIdx.x >> 4;    // 0..15 edge-parallel group
    int l  = threadIdx.x & 15;    // (b, c4)
    int b = l >> 2, c4 = l & 3;
    const float4* sb = (const float4*)h2C + b * 4 + c4;
    for (int s = blockIdx.x; s < r2c; s += gridDim.x) {
        int L = w_cntC[s]; if (L > WDEG) L = WDEG;
        const int2* pr = w_pairs + (size_t)s * WDEG;
        float4 acc = make_float4(0.f, 0.f, 0.f, 0.f);
        for (int i = e0; i < L; i += 16) {
            int2 p = pr[i];
            int hs = n1slot[p.x];               // col is n1 by construction
            float v = __int_as_float(p.y);
            if (hs >= 0 && hs < N1_CAP) {
                float4 sv = sb[(size_t)hs * 16];
                acc.x += v * sv.x; acc.y += v * sv.y;
                acc.z += v * sv.z; acc.w += v * sv.w;
            }
        }
        red[e0][l] = acc;
        __syncthreads();
#pragma unroll
        for (int off = 8; off >= 1; off >>= 1) {
            if (e0 < off) {
                float4 o = red[e0 + off][l];
                float4 a = red[e0][l];
                a.x += o.x; a.y += o.y; a.z += o.z; a.w += o.w;
                red[e0][l] = a;
            }
            __syncthreads();
        }
        if (e0 == 0)
            ((float4*)t2C)[(size_t)s * 16 + l] = red[0][l];
        __syncthreads();
    }
}

// ---- heads: x2 accumulation + regression heads, ONE small block ----
__global__ void heads(const int* __restrict__ rslot, const int* __restrict__ tails,
                      const float* __restrict__ t2C, const int2* __restrict__ x2list,
                      const float* __restrict__ diag2,
                      const float* __restrict__ rw1, const float* __restrict__ rb1,
                      const float* __restrict__ rw2, const float* __restrict__ rb2,
                      float* __restrict__ out) {
    int cnt = tails[0]; if (cnt > X2_CAP) cnt = X2_CAP;
    int g = threadIdx.x >> 6, l = threadIdx.x & 63;   // 16 groups of 64 lanes
    int b = l >> 4, c = l & 15;
    float a0 = 0.f, a1 = 0.f;
    for (int i = g; i < cnt; i += 16) {
        int2 rec = x2list[i];
        int col = rec.x >> 1;
        int s = rslot[col];
        float coef = __int_as_float(rec.y) * diag2[col];
        float v = (s >= 0 && s < R2_CAP) ? t2C[(size_t)s * 64 + b * 16 + c] * coef : 0.f;
        if (rec.x & 1) a1 += v; else a0 += v;
    }
    __shared__ float red0[16][64], red1[16][64], xs[2][64];
    red0[g][l] = a0; red1[g][l] = a1;
    __syncthreads();
    if (threadIdx.x < 64) {
        float s0 = 0.f, s1 = 0.f;
#pragma unroll
        for (int gg = 0; gg < 16; ++gg) { s0 += red0[gg][threadIdx.x]; s1 += red1[gg][threadIdx.x]; }
        xs[0][threadIdx.x] = s0; xs[1][threadIdx.x] = s1;
    }
    __syncthreads();
    if (threadIdx.x < 8) {
        int bb = threadIdx.x >> 1, which = threadIdx.x & 1;
        const float* w = which ? rw2 : rw1;
        float acc = which ? rb2[0] : rb1[0];
        for (int k = 0; k < 16; ++k) {
            float xv = xs[which][bb * 16 + k];
            xv = xv > 0.f ? xv : NEG_SLOPE * xv;
            acc += xv * w[k];
        }
        out[bb * 2 + which] = acc;
    }
}

extern "C" void kernel_launch(void* const* d_in, const int* in_sizes, int n_in,
                              void* d_out, int out_size, void* d_ws, size_t ws_size,
                              hipStream_t stream) {
    const int*   w_rows  = (const int*)d_in[0];
    const int*   w_cols  = ((const int*)d_in[0]) + E;
    const float* w_val   = (const float*)d_in[1];
    const int*   wi_rows = (const int*)d_in[2];
    const int*   wi_cols = ((const int*)d_in[2]) + E;
    const float* wi_val  = (const float*)d_in[3];
    const float* x       = (const float*)d_in[4];
    const float* W1      = (const float*)d_in[5];
    const float* diag1   = (const float*)d_in[6];
    const float* W2      = (const float*)d_in[7];
    const float* diag2   = (const float*)d_in[8];
    const float* rw1     = (const float*)d_in[9];
    const float* rb1     = (const float*)d_in[10];
    const float* rw2     = (const float*)d_in[11];
    const float* rb2     = (const float*)d_in[12];
    float* out = (float*)d_out;

    // ---------------- workspace layout (~56 MB) ----------------
    float* t1C = (float*)d_ws;                       // [RS_CAP][128] (25.2 MB)
    float* h2C = t1C + (size_t)RS_CAP * 128;         // [N1_CAP][64]  (1 MB)
    float* t2C = h2C + (size_t)N1_CAP * 64;          // [R2_CAP][64]  (1 MB)
    int* ip = (int*)(t2C + (size_t)R2_CAP * 64);
    // zeroed block (contiguous, ZWORDS words):
    int* w_cntC  = ip; ip += RS_CAP;
    int* wi_cntC = ip; ip += N1_CAP;
    unsigned* bitsRS = (unsigned*)ip; ip += RBW;
    unsigned* bitsN1 = (unsigned*)ip; ip += NBW;
    int* tails = ip; ip += 8;
    // un-zeroed:
    int* rslot  = ip; ip += R;
    int* n1slot = ip; ip += N;
    int2* x2list = (int2*)ip; ip += 2 * X2_CAP;
    int2* w_pairs  = (int2*)ip; ip += 2 * (size_t)RS_CAP * WDEG;   // 25.2 MB
    int2* wi_pairs = (int2*)ip; ip += 2 * (size_t)N1_CAP * WIDEG;  // 3.1 MB

    const int e4 = E / 4;
    const int blk = 256;
    const int scanGrid = (e4 + blk - 1) / blk;

    (void)hipMemsetAsync(w_cntC, 0, (size_t)ZWORDS * sizeof(int), stream);

    scanA<<<scanGrid, blk, 0, stream>>>((const int4*)wi_rows, (const int4*)wi_cols,
                                        (const float4*)wi_val, bitsRS, rslot,
                                        x2list, tails, e4);
    scanB<<<scanGrid, blk, 0, stream>>>((const int4*)w_rows, (const int4*)w_cols,
                                        bitsRS, bitsN1, n1slot, tails, e4);
    scanC<<<scanGrid, blk, 0, stream>>>((const int4*)wi_rows, (const int4*)wi_cols,
                                        (const float4*)wi_val, diag1, bitsN1, n1slot,
                                        bitsRS, rslot, wi_cntC, wi_pairs, tails, e4);
    scanD<<<scanGrid, blk, 0, stream>>>((const int4*)w_rows, (const int4*)w_cols,
                                        (const float4*)w_val, bitsRS, rslot,
                                        w_cntC, w_pairs, e4);
    gather_t1<<<2048, blk, 0, stream>>>(x, t1C, w_cntC, w_pairs, tails);
    x1mlp<<<1024, blk, 0, stream>>>(W1, W2, tails, wi_cntC, wi_pairs, rslot, t1C, h2C);
    t2gather<<<128, blk, 0, stream>>>(h2C, w_cntC, w_pairs, n1slot, tails, t2C);
    heads<<<1, 1024, 0, stream>>>(rslot, tails, t2C, x2list, diag2,
                                  rw1, rb1, rw2, rb2, out);
}

// Round 11
// 239.862 us; speedup vs baseline: 1.6058x; 1.0084x over previous
//
#include <hip/hip_runtime.h>

#define NEG_SLOPE 0.2f

static const int B = 4, N = 50000, R = 100000, E = 1600000;
static const int X2_CAP = 4096;     // x2 edge records (expected ~64)
static const int R2_CAP = 4096;     // r2 rows (expected ~64)
static const int N1_CAP = 4096;     // n1 nodes (expected ~1k)
static const int RS_CAP = 49152;    // row slots, r2 + r1 (expected ~28k)
static const int WDEG  = 48;        // w-CSR slab per slot (mean deg 16, P(>48)~1e-11)
static const int WIDEG = 96;        // wi-CSR slab per n1 slot (mean deg 32)
static const int RBW = 3200;        // bit-words for R rows
static const int NBW = 1600;        // bit-words for N nodes
static const int ZWORDS = RS_CAP + N1_CAP + RBW + NBW + 8;
// tails: [0]=x2tail [1]=unused [2]=n1tail [3]=slotTail [4]=r2c snapshot

// ---- scanA: wi edges with row>=N-2 -> x2list + r2 rows get slots [0,r2c) ----
__global__ void scanA(const int4* __restrict__ wi_rows4, const int4* __restrict__ wi_cols4,
                      const float4* __restrict__ wi_val4,
                      unsigned* __restrict__ bitsRS, int* __restrict__ rslot,
                      int2* __restrict__ x2list, int* __restrict__ tails, int e4) {
    int i = blockIdx.x * blockDim.x + threadIdx.x;
    if (i >= e4) return;
    int4 r = wi_rows4[i];
    int rr[4] = {r.x, r.y, r.z, r.w};
    bool any = false;
#pragma unroll
    for (int j = 0; j < 4; ++j) any = any || (rr[j] >= N - 2);
    if (!any) return;
    int4 c = wi_cols4[i];
    float4 v = wi_val4[i];
    int cc[4] = {c.x, c.y, c.z, c.w};
    float vv[4] = {v.x, v.y, v.z, v.w};
#pragma unroll
    for (int j = 0; j < 4; ++j) {
        if (rr[j] >= N - 2) {
            int col = cc[j];
            unsigned m = 1u << (col & 31);
            unsigned old = atomicOr(&bitsRS[col >> 5], m);
            if (!(old & m)) {
                int s = atomicAdd(&tails[3], 1);   // ~64 winners: negligible
                if (s < RS_CAP) rslot[col] = s;
            }
            int q = atomicAdd(&tails[0], 1);
            if (q < X2_CAP)
                x2list[q] = make_int2(col * 2 + (rr[j] - (N - 2)),
                                      __float_as_int(vv[j]));
        }
    }
}

// ---- scanB: w edges with row in r2 (bitsRS) -> n1 set, slot via block-agg ----
__global__ void scanB(const int4* __restrict__ w_rows4, const int4* __restrict__ w_cols4,
                      const unsigned* __restrict__ bitsRS, unsigned* __restrict__ bitsN1,
                      int* __restrict__ n1slot, int* __restrict__ tails, int e4) {
    __shared__ int lcount, gbase;
    __shared__ int buf[1024];
    if (threadIdx.x == 0) {
        lcount = 0;
        if (blockIdx.x == 0) tails[4] = tails[3];   // snapshot r2c
    }
    __syncthreads();
    int lane = threadIdx.x & 63;
    int i = blockIdx.x * blockDim.x + threadIdx.x;
    int4 r = make_int4(-1, -1, -1, -1);
    if (i < e4) r = w_rows4[i];
    int rr[4] = {r.x, r.y, r.z, r.w};
    unsigned fb[4];
#pragma unroll
    for (int j = 0; j < 4; ++j)
        fb[j] = (rr[j] >= 0) ? ((bitsRS[rr[j] >> 5] >> (rr[j] & 31)) & 1u) : 0u;
    bool anyf = (fb[0] | fb[1] | fb[2] | fb[3]) != 0u;
    int4 c = make_int4(0, 0, 0, 0);
    if (anyf) c = w_cols4[i];
    int cc[4] = {c.x, c.y, c.z, c.w};
#pragma unroll
    for (int j = 0; j < 4; ++j) {
        bool isnew = false;
        int n = 0;
        if (fb[j]) {
            n = cc[j];
            unsigned m = 1u << (n & 31);
            unsigned old = atomicOr(&bitsN1[n >> 5], m);
            isnew = (old & m) == 0u;
        }
        unsigned long long mb = __ballot(isnew);
        if (mb) {
            int leader = __ffsll(mb) - 1;
            int b0 = 0;
            if (lane == leader) b0 = atomicAdd(&lcount, __popcll(mb));
            b0 = __shfl(b0, leader);
            if (isnew) {
                int p = b0 + __popcll(mb & ((1ull << lane) - 1));
                if (p < 1024) buf[p] = n;
            }
        }
    }
    __syncthreads();
    int lc = lcount; if (lc > 1024) lc = 1024;
    if (threadIdx.x == 0 && lc > 0) gbase = atomicAdd(&tails[2], lc);
    __syncthreads();
    for (int t = threadIdx.x; t < lc; t += blockDim.x) {
        int slot = gbase + t;
        if (slot < N1_CAP) n1slot[buf[t]] = slot;
    }
}

// ---- scanC: wi edges with node-row in n1 -> wi-place + r1 slots (block-agg) ----
__global__ void scanC(const int4* __restrict__ wi_rows4, const int4* __restrict__ wi_cols4,
                      const float4* __restrict__ wi_val4, const float* __restrict__ diag1,
                      const unsigned* __restrict__ bitsN1, const int* __restrict__ n1slot,
                      unsigned* __restrict__ bitsRS, int* __restrict__ rslot,
                      int* __restrict__ wi_cntC, int2* __restrict__ wi_pairs,
                      int* __restrict__ tails, int e4) {
    __shared__ int lcount, gbase;
    __shared__ int buf[1024];
    if (threadIdx.x == 0) lcount = 0;
    __syncthreads();
    int lane = threadIdx.x & 63;
    int i = blockIdx.x * blockDim.x + threadIdx.x;
    int4 r = make_int4(-1, -1, -1, -1);
    if (i < e4) r = wi_rows4[i];
    int rr[4] = {r.x, r.y, r.z, r.w};
    unsigned fb[4];
#pragma unroll
    for (int j = 0; j < 4; ++j)
        fb[j] = (rr[j] >= 0) ? ((bitsN1[rr[j] >> 5] >> (rr[j] & 31)) & 1u) : 0u;
    bool anyf = (fb[0] | fb[1] | fb[2] | fb[3]) != 0u;
    int4 c = make_int4(0, 0, 0, 0);
    float4 v = make_float4(0.f, 0.f, 0.f, 0.f);
    if (anyf) { c = wi_cols4[i]; v = wi_val4[i]; }
    int cc[4] = {c.x, c.y, c.z, c.w};
    float vv[4] = {v.x, v.y, v.z, v.w};
#pragma unroll
    for (int j = 0; j < 4; ++j) {
        bool isnew = false;
        int col = 0;
        if (fb[j]) {
            col = cc[j];
            float cf = vv[j] * diag1[col];
            int slot = n1slot[rr[j]];
            if (slot >= 0 && slot < N1_CAP) {
                int pos = atomicAdd(&wi_cntC[slot], 1);
                if (pos < WIDEG)
                    wi_pairs[(size_t)slot * WIDEG + pos] =
                        make_int2(col, __float_as_int(cf));
            }
            unsigned m = 1u << (col & 31);
            unsigned old = atomicOr(&bitsRS[col >> 5], m);
            isnew = (old & m) == 0u;
        }
        unsigned long long mb = __ballot(isnew);
        if (mb) {
            int leader = __ffsll(mb) - 1;
            int b0 = 0;
            if (lane == leader) b0 = atomicAdd(&lcount, __popcll(mb));
            b0 = __shfl(b0, leader);
            if (isnew) {
                int p = b0 + __popcll(mb & ((1ull << lane) - 1));
                if (p < 1024) buf[p] = col;
            }
        }
    }
    __syncthreads();
    int lc = lcount; if (lc > 1024) lc = 1024;
    if (threadIdx.x == 0 && lc > 0) gbase = atomicAdd(&tails[3], lc);
    __syncthreads();
    for (int t = threadIdx.x; t < lc; t += blockDim.x) {
        int s = gbase + t;
        if (s < RS_CAP) rslot[buf[t]] = s;
    }
}

// ---- scanD: w edges with slotted row (r1|r2) -> compact w-slab place ----
// Unconditional cols/vals loads: 74% of groups have >=1 slotted edge, so the
// branch saved little traffic and serialized the loads behind the flag check.
__global__ void scanD(const int4* __restrict__ w_rows4, const int4* __restrict__ w_cols4,
                      const float4* __restrict__ w_val4,
                      const unsigned* __restrict__ bitsRS, const int* __restrict__ rslot,
                      int* __restrict__ w_cntC, int2* __restrict__ w_pairs, int e4) {
    int i = blockIdx.x * blockDim.x + threadIdx.x;
    if (i >= e4) return;
    int4 r = w_rows4[i];
    int4 c = w_cols4[i];
    float4 v = w_val4[i];
    int rr[4] = {r.x, r.y, r.z, r.w};
    int cc[4] = {c.x, c.y, c.z, c.w};
    float vv[4] = {v.x, v.y, v.z, v.w};
    unsigned fb[4];
#pragma unroll
    for (int j = 0; j < 4; ++j) fb[j] = (bitsRS[rr[j] >> 5] >> (rr[j] & 31)) & 1u;
    int s[4];
#pragma unroll
    for (int j = 0; j < 4; ++j) s[j] = fb[j] ? rslot[rr[j]] : RS_CAP;
    int pos[4];
#pragma unroll
    for (int j = 0; j < 4; ++j)
        pos[j] = (fb[j] && s[j] >= 0 && s[j] < RS_CAP) ? atomicAdd(&w_cntC[s[j]], 1) : WDEG;
#pragma unroll
    for (int j = 0; j < 4; ++j)
        if (pos[j] < WDEG)
            w_pairs[(size_t)s[j] * WDEG + pos[j]] =
                make_int2(cc[j], __float_as_int(vv[j]));
}

// ---- gather_t1: per slot, t1C[s] = sum_w v * x[col]  (32 threads/slot) ----
__global__ void gather_t1(const float* __restrict__ x, float* __restrict__ t1C,
                          const int* __restrict__ w_cntC, const int2* __restrict__ w_pairs,
                          const int* __restrict__ tails) {
    int tot = tails[3]; if (tot > RS_CAP) tot = RS_CAP;
    int total = tot * 32;
    int gstride = gridDim.x * blockDim.x;
    for (int idx = blockIdx.x * blockDim.x + threadIdx.x; idx < total; idx += gstride) {
        int s = idx >> 5;
        int rem = idx & 31;
        int c4 = rem & 7;
        int b = rem >> 3;
        int L = w_cntC[s]; if (L > WDEG) L = WDEG;
        const int2* pr = w_pairs + (size_t)s * WDEG;
        const float4* sb = (const float4*)x + (size_t)b * N * 8 + c4;
        float4 acc = make_float4(0.f, 0.f, 0.f, 0.f);
        int i = 0;
        int L4 = L & ~3;
        for (; i < L4; i += 4) {
            int2 p0 = pr[i + 0];
            int2 p1 = pr[i + 1];
            int2 p2 = pr[i + 2];
            int2 p3 = pr[i + 3];
            float4 s0 = sb[(size_t)p0.x * 8];
            float4 s1 = sb[(size_t)p1.x * 8];
            float4 s2 = sb[(size_t)p2.x * 8];
            float4 s3 = sb[(size_t)p3.x * 8];
            float v0 = __int_as_float(p0.y), v1 = __int_as_float(p1.y);
            float v2 = __int_as_float(p2.y), v3 = __int_as_float(p3.y);
            acc.x += v0 * s0.x + v1 * s1.x + v2 * s2.x + v3 * s3.x;
            acc.y += v0 * s0.y + v1 * s1.y + v2 * s2.y + v3 * s3.y;
            acc.z += v0 * s0.z + v1 * s1.z + v2 * s2.z + v3 * s3.z;
            acc.w += v0 * s0.w + v1 * s1.w + v2 * s2.w + v3 * s3.w;
        }
        for (; i < L; ++i) {
            int2 p = pr[i];
            float4 sv = sb[(size_t)p.x * 8];
            float v = __int_as_float(p.y);
            acc.x += v * sv.x; acc.y += v * sv.y; acc.z += v * sv.z; acc.w += v * sv.w;
        }
        ((float4*)t1C)[(size_t)s * 32 + b * 8 + c4] = acc;
    }
}

// ---- x1mlp: per n1 slot, u = wi-agg(t1C); h2C = lrelu(u@W1)@W2 ----
__global__ void __launch_bounds__(256) x1mlp(
        const float* __restrict__ W1, const float* __restrict__ W2,
        const int* __restrict__ tails,
        const int* __restrict__ wi_cntC, const int2* __restrict__ wi_pairs,
        const int* __restrict__ rslot, const float* __restrict__ t1C,
        float* __restrict__ h2C) {
    __shared__ float W1s[1024], W2s[512];
    __shared__ float uls[8][128];
    __shared__ float ufin[128], x1ls[128];
    for (int i = threadIdx.x; i < 1024; i += 256) W1s[i] = W1[i];
    for (int i = threadIdx.x; i < 512; i += 256) W2s[i] = W2[i];
    int n1c = tails[2]; if (n1c > N1_CAP) n1c = N1_CAP;
    int g = threadIdx.x >> 5, t32 = threadIdx.x & 31;
    int b = t32 >> 3, c4 = t32 & 7;
    const float4* t1f4 = (const float4*)t1C;
    for (int s = blockIdx.x; s < n1c; s += gridDim.x) {
        int L = wi_cntC[s]; if (L > WIDEG) L = WIDEG;
        const int2* wip = wi_pairs + (size_t)s * WIDEG;
        float4 acc = make_float4(0.f, 0.f, 0.f, 0.f);
        for (int e = g; e < L; e += 8) {
            int2 pe = wip[e];
            int rs = rslot[pe.x];
            float coef = __int_as_float(pe.y);        // diag1 already folded
            if (rs >= 0 && rs < RS_CAP) {
                float4 tv = t1f4[(size_t)rs * 32 + b * 8 + c4];
                acc.x += coef * tv.x; acc.y += coef * tv.y;
                acc.z += coef * tv.z; acc.w += coef * tv.w;
            }
        }
        float* up = &uls[g][b * 32 + c4 * 4];
        up[0] = acc.x; up[1] = acc.y; up[2] = acc.z; up[3] = acc.w;
        __syncthreads();
        if (threadIdx.x < 128) {
            float sum = 0.f;
#pragma unroll
            for (int gg = 0; gg < 8; ++gg) sum += uls[gg][threadIdx.x];
            ufin[threadIdx.x] = sum;
        }
        __syncthreads();
        if (threadIdx.x < 128) {
            int bb = threadIdx.x >> 5, c = threadIdx.x & 31;
            const float* ur = &ufin[bb * 32];
            float o = 0.f;
#pragma unroll
            for (int k = 0; k < 32; ++k) o += ur[k] * W1s[k * 32 + c];
            x1ls[threadIdx.x] = o > 0.f ? o : NEG_SLOPE * o;
        }
        __syncthreads();
        if (threadIdx.x < 64) {
            int bb = threadIdx.x >> 4, c = threadIdx.x & 15;
            const float* xr = &x1ls[bb * 32];
            float o = 0.f;
#pragma unroll
            for (int k = 0; k < 32; ++k) o += xr[k] * W2s[k * 16 + c];
            h2C[(size_t)s * 64 + bb * 16 + c] = o;
        }
        __syncthreads();
    }
}

// ---- t2gather: per r2 slot, 256 threads = 16 edge-par x 16 (b,c4) lanes ----
__global__ void __launch_bounds__(256) t2gather(
        const float* __restrict__ h2C,
        const int* __restrict__ w_cntC, const int2* __restrict__ w_pairs,
        const int* __restrict__ n1slot, const int* __restrict__ tails,
        float* __restrict__ t2C) {
    __shared__ float4 red[16][16];
    int r2c = tails[4]; if (r2c > R2_CAP) r2c = R2_CAP;
    int e0 = threadIdx.x >> 4;    // 0..15 edge-parallel group
    int l  = threadIdx.x & 15;    // (b, c4)
    int b = l >> 2, c4 = l & 3;
    const float4* sb = (const float4*)h2C + b * 4 + c4;
    for (int s = blockIdx.x; s < r2c; s += gridDim.x) {
        int L = w_cntC[s]; if (L > WDEG) L = WDEG;
        const int2* pr = w_pairs + (size_t)s * WDEG;
        float4 acc = make_float4(0.f, 0.f, 0.f, 0.f);
        for (int i = e0; i < L; i += 16) {
            int2 p = pr[i];
            int hs = n1slot[p.x];               // col is n1 by construction
            float v = __int_as_float(p.y);
            if (hs >= 0 && hs < N1_CAP) {
                float4 sv = sb[(size_t)hs * 16];
                acc.x += v * sv.x; acc.y += v * sv.y;
                acc.z += v * sv.z; acc.w += v * sv.w;
            }
        }
        red[e0][l] = acc;
        __syncthreads();
#pragma unroll
        for (int off = 8; off >= 1; off >>= 1) {
            if (e0 < off) {
                float4 o = red[e0 + off][l];
                float4 a = red[e0][l];
                a.x += o.x; a.y += o.y; a.z += o.z; a.w += o.w;
                red[e0][l] = a;
            }
            __syncthreads();
        }
        if (e0 == 0)
            ((float4*)t2C)[(size_t)s * 16 + l] = red[0][l];
        __syncthreads();
    }
}

// ---- heads: x2 accumulation + regression heads, ONE small block ----
__global__ void heads(const int* __restrict__ rslot, const int* __restrict__ tails,
                      const float* __restrict__ t2C, const int2* __restrict__ x2list,
                      const float* __restrict__ diag2,
                      const float* __restrict__ rw1, const float* __restrict__ rb1,
                      const float* __restrict__ rw2, const float* __restrict__ rb2,
                      float* __restrict__ out) {
    int cnt = tails[0]; if (cnt > X2_CAP) cnt = X2_CAP;
    int g = threadIdx.x >> 6, l = threadIdx.x & 63;   // 16 groups of 64 lanes
    int b = l >> 4, c = l & 15;
    float a0 = 0.f, a1 = 0.f;
    for (int i = g; i < cnt; i += 16) {
        int2 rec = x2list[i];
        int col = rec.x >> 1;
        int s = rslot[col];
        float coef = __int_as_float(rec.y) * diag2[col];
        float v = (s >= 0 && s < R2_CAP) ? t2C[(size_t)s * 64 + b * 16 + c] * coef : 0.f;
        if (rec.x & 1) a1 += v; else a0 += v;
    }
    __shared__ float red0[16][64], red1[16][64], xs[2][64];
    red0[g][l] = a0; red1[g][l] = a1;
    __syncthreads();
    if (threadIdx.x < 64) {
        float s0 = 0.f, s1 = 0.f;
#pragma unroll
        for (int gg = 0; gg < 16; ++gg) { s0 += red0[gg][threadIdx.x]; s1 += red1[gg][threadIdx.x]; }
        xs[0][threadIdx.x] = s0; xs[1][threadIdx.x] = s1;
    }
    __syncthreads();
    if (threadIdx.x < 8) {
        int bb = threadIdx.x >> 1, which = threadIdx.x & 1;
        const float* w = which ? rw2 : rw1;
        float acc = which ? rb2[0] : rb1[0];
        for (int k = 0; k < 16; ++k) {
            float xv = xs[which][bb * 16 + k];
            xv = xv > 0.f ? xv : NEG_SLOPE * xv;
            acc += xv * w[k];
        }
        out[bb * 2 + which] = acc;
    }
}

extern "C" void kernel_launch(void* const* d_in, const int* in_sizes, int n_in,
                              void* d_out, int out_size, void* d_ws, size_t ws_size,
                              hipStream_t stream) {
    const int*   w_rows  = (const int*)d_in[0];
    const int*   w_cols  = ((const int*)d_in[0]) + E;
    const float* w_val   = (const float*)d_in[1];
    const int*   wi_rows = (const int*)d_in[2];
    const int*   wi_cols = ((const int*)d_in[2]) + E;
    const float* wi_val  = (const float*)d_in[3];
    const float* x       = (const float*)d_in[4];
    const float* W1      = (const float*)d_in[5];
    const float* diag1   = (const float*)d_in[6];
    const float* W2      = (const float*)d_in[7];
    const float* diag2   = (const float*)d_in[8];
    const float* rw1     = (const float*)d_in[9];
    const float* rb1     = (const float*)d_in[10];
    const float* rw2     = (const float*)d_in[11];
    const float* rb2     = (const float*)d_in[12];
    float* out = (float*)d_out;

    // ---------------- workspace layout (~50 MB) ----------------
    float* t1C = (float*)d_ws;                       // [RS_CAP][128] (25.2 MB)
    float* h2C = t1C + (size_t)RS_CAP * 128;         // [N1_CAP][64]  (1 MB)
    float* t2C = h2C + (size_t)N1_CAP * 64;          // [R2_CAP][64]  (1 MB)
    int* ip = (int*)(t2C + (size_t)R2_CAP * 64);
    // zeroed block (contiguous, ZWORDS words):
    int* w_cntC  = ip; ip += RS_CAP;
    int* wi_cntC = ip; ip += N1_CAP;
    unsigned* bitsRS = (unsigned*)ip; ip += RBW;
    unsigned* bitsN1 = (unsigned*)ip; ip += NBW;
    int* tails = ip; ip += 8;
    // un-zeroed:
    int* rslot  = ip; ip += R;
    int* n1slot = ip; ip += N;
    int2* x2list = (int2*)ip; ip += 2 * X2_CAP;
    int2* w_pairs  = (int2*)ip; ip += 2 * (size_t)RS_CAP * WDEG;   // 18.9 MB
    int2* wi_pairs = (int2*)ip; ip += 2 * (size_t)N1_CAP * WIDEG;  // 3.1 MB

    const int e4 = E / 4;
    const int blk = 256;
    const int scanGrid = (e4 + blk - 1) / blk;

    (void)hipMemsetAsync(w_cntC, 0, (size_t)ZWORDS * sizeof(int), stream);

    scanA<<<scanGrid, blk, 0, stream>>>((const int4*)wi_rows, (const int4*)wi_cols,
                                        (const float4*)wi_val, bitsRS, rslot,
                                        x2list, tails, e4);
    scanB<<<scanGrid, blk, 0, stream>>>((const int4*)w_rows, (const int4*)w_cols,
                                        bitsRS, bitsN1, n1slot, tails, e4);
    scanC<<<scanGrid, blk, 0, stream>>>((const int4*)wi_rows, (const int4*)wi_cols,
                                        (const float4*)wi_val, diag1, bitsN1, n1slot,
                                        bitsRS, rslot, wi_cntC, wi_pairs, tails, e4);
    scanD<<<scanGrid, blk, 0, stream>>>((const int4*)w_rows, (const int4*)w_cols,
                                        (const float4*)w_val, bitsRS, rslot,
                                        w_cntC, w_pairs, e4);
    gather_t1<<<4096, blk, 0, stream>>>(x, t1C, w_cntC, w_pairs, tails);
    x1mlp<<<1024, blk, 0, stream>>>(W1, W2, tails, wi_cntC, wi_pairs, rslot, t1C, h2C);
    t2gather<<<128, blk, 0, stream>>>(h2C, w_cntC, w_pairs, n1slot, tails, t2C);
    heads<<<1, 1024, 0, stream>>>(rslot, tails, t2C, x2list, diag2,
                                  rw1, rb1, rw2, rb2, out);
}